// Round 1
// baseline (434.745 us; speedup 1.0000x reference)
//
#include <hip/hip_runtime.h>

#define TPB 256

typedef __attribute__((ext_vector_type(8))) short          bf8_t;   // 8 x bf16 (4 VGPRs)
typedef __attribute__((ext_vector_type(4))) float          f4_t;
typedef __attribute__((ext_vector_type(4))) unsigned short us4_t;

__device__ __forceinline__ unsigned short f2bf(float f) {
    union { float f; unsigned u; } v; v.f = f;
    unsigned r = v.u + 0x7FFFu + ((v.u >> 16) & 1u);   // round-to-nearest-even
    return (unsigned short)(r >> 16);
}

// ---------------- graph build (CSR by dst, rebuilt every call) ----------------

__global__ void k_count(const int* __restrict__ ei, int E, int* __restrict__ cnt) {
    int e = blockIdx.x * TPB + threadIdx.x;
    if (e < E) atomicAdd(&cnt[ei[E + e]], 1);
}

__global__ void k_blocksum(const int* __restrict__ cnt, int n, int* __restrict__ bsum) {
    __shared__ int s[TPB];
    int t = threadIdx.x, i = blockIdx.x * TPB + t;
    s[t] = (i < n) ? cnt[i] : 0;
    __syncthreads();
    for (int off = TPB / 2; off > 0; off >>= 1) {
        if (t < off) s[t] += s[t + off];
        __syncthreads();
    }
    if (t == 0) bsum[blockIdx.x] = s[0];
}

__global__ void k_scan_bsum(int* __restrict__ bsum, int nb) {
    __shared__ int s[512];
    int t = threadIdx.x;
    int v = (t < nb) ? bsum[t] : 0;
    s[t] = v; __syncthreads();
    for (int off = 1; off < 512; off <<= 1) {
        int x = (t >= off) ? s[t - off] : 0;
        __syncthreads();
        s[t] += x;
        __syncthreads();
    }
    if (t < nb) bsum[t] = s[t] - v;   // exclusive block offsets
}

__global__ void k_rowptr(const int* __restrict__ cnt, const int* __restrict__ bsum, int n, int E,
                         int* __restrict__ rowptr, int* __restrict__ cursor,
                         float* __restrict__ dinv, float* __restrict__ dis) {
    __shared__ int s[TPB];
    int t = threadIdx.x, i = blockIdx.x * TPB + t;
    int v = (i < n) ? cnt[i] : 0;
    s[t] = v; __syncthreads();
    for (int off = 1; off < TPB; off <<= 1) {
        int x = (t >= off) ? s[t - off] : 0;
        __syncthreads();
        s[t] += x;
        __syncthreads();
    }
    if (i < n) {
        int start = bsum[blockIdx.x] + s[t] - v;
        rowptr[i] = start;
        cursor[i] = start;
        float d = (float)(v + 1);      // + self loop; deg >= 1 always
        dinv[i] = 1.0f / d;
        dis[i]  = rsqrtf(d);
    }
    if (i == 0) rowptr[n] = E;
}

__global__ void k_fill(const int* __restrict__ ei, int E,
                       int* __restrict__ cursor, int* __restrict__ col) {
    int e = blockIdx.x * TPB + threadIdx.x;
    if (e < E) {
        int src = ei[e], dst = ei[E + e];
        int p = atomicAdd(&cursor[dst], 1);
        col[p] = src;
    }
}

// ---------------- conversions ----------------

__global__ void k_xconv(const float* __restrict__ x, unsigned short* __restrict__ xb, long total4) {
    long i = (long)blockIdx.x * TPB + threadIdx.x;
    if (i < total4) {
        f4_t v = *(const f4_t*)(x + i * 4);
        us4_t o;
        o.x = f2bf(v.x); o.y = f2bf(v.y); o.z = f2bf(v.z); o.w = f2bf(v.w);
        *(us4_t*)(xb + i * 4) = o;
    }
}

// transpose+convert all 6 weight matrices: T[m*K + k] = bf16(W[k*M + m])
__global__ void k_wconv(const float* W1, const float* Wr1, const float* W2, const float* Wr2,
                        const float* Wmu, const float* Wls,
                        unsigned short* T1, unsigned short* Tr1, unsigned short* T2,
                        unsigned short* Tr2, unsigned short* Tmu, unsigned short* Tls) {
    const float* W; unsigned short* T; int K, M;
    switch (blockIdx.y) {
        case 0: W = W1;  T = T1;  K = 128; M = 96; break;
        case 1: W = Wr1; T = Tr1; K = 128; M = 96; break;
        case 2: W = W2;  T = T2;  K = 96;  M = 64; break;
        case 3: W = Wr2; T = Tr2; K = 96;  M = 64; break;
        case 4: W = Wmu; T = Tmu; K = 64;  M = 32; break;
        default:W = Wls; T = Tls; K = 64;  M = 32; break;
    }
    int idx = blockIdx.x * TPB + threadIdx.x;
    if (idx < K * M) {
        int m = idx / K, k = idx % K;
        T[idx] = f2bf(W[k * M + m]);
    }
}

// ---------------- bf16 MFMA GEMM: Y[n][c0+col] = sum_k Xb[n][k] * W[k][col] ----------------
// Xb: N x K bf16 row-major.  WT: M x K bf16 (transposed weight).  Y: fp32, row stride ldY.
// Block = 4 waves -> 64 nodes x 16 cols per block. Verified layouts (m89/m120):
//   A-frag: m = lane&15, k = quad*8+j ; B-frag: n = lane&15, k = quad*8+j
//   C/D:    col = lane&15, row = quad*4 + reg
__global__ __launch_bounds__(TPB) void k_gemm(const unsigned short* __restrict__ Xb,
                                              const unsigned short* __restrict__ WT,
                                              float* __restrict__ Y,
                                              int K, int ldY, int c0, int n) {
    int lane = threadIdx.x & 63;
    int wave = threadIdx.x >> 6;
    int quad = lane >> 4;
    int l15  = lane & 15;
    int base = (blockIdx.x * 4 + wave) * 16;
    int rA = base + l15; if (rA > n - 1) rA = n - 1;
    const unsigned short* ap = Xb + (size_t)rA * K + quad * 8;
    const unsigned short* bp = WT + (size_t)(blockIdx.y * 16 + l15) * K + quad * 8;
    f4_t acc = {0.f, 0.f, 0.f, 0.f};
    for (int k0 = 0; k0 < K; k0 += 32) {
        bf8_t a = *(const bf8_t*)(ap + k0);
        bf8_t b = *(const bf8_t*)(bp + k0);
        acc = __builtin_amdgcn_mfma_f32_16x16x32_bf16(a, b, acc, 0, 0, 0);
    }
    int colg = c0 + blockIdx.y * 16 + l15;
    int row  = base + quad * 4;
#pragma unroll
    for (int r = 0; r < 4; r++) {
        if (row + r < n) Y[(size_t)(row + r) * ldY + colg] = acc[r];
    }
}

// ---------------- ClusterGCN aggregation ----------------
// Hb[i] = bf16( relu( dinv[i] * (sum_{src->i} Y[src] + Y[i]) + R[i] + bias ) )
template <int M, int GRP>
__global__ __launch_bounds__(TPB) void k_aggc(const float* __restrict__ Y, const float* __restrict__ R,
                                              const float* __restrict__ bias, const float* __restrict__ dinv,
                                              const int* __restrict__ rowptr, const int* __restrict__ col,
                                              unsigned short* __restrict__ Hb, int n) {
    int g = blockIdx.x * (TPB / GRP) + threadIdx.x / GRP;
    int l = threadIdx.x & (GRP - 1);
    if (g >= n) return;
    int c = l * 4;
    int r0 = rowptr[g], r1 = rowptr[g + 1];
    f4_t acc = {0.f, 0.f, 0.f, 0.f};
    if (c < M) acc = *(const f4_t*)(Y + (size_t)g * M + c);
    for (int e = r0; e < r1; ++e) {
        int s = col[e];
        if (c < M) acc += *(const f4_t*)(Y + (size_t)s * M + c);
    }
    if (c < M) {
        float di = dinv[g];
        f4_t rr = *(const f4_t*)(R + (size_t)g * M + c);
        f4_t bb = *(const f4_t*)(bias + c);
        f4_t h  = acc * di + rr + bb;
        us4_t o;
        o.x = f2bf(fmaxf(h.x, 0.f));
        o.y = f2bf(fmaxf(h.y, 0.f));
        o.z = f2bf(fmaxf(h.z, 0.f));
        o.w = f2bf(fmaxf(h.w, 0.f));
        *(us4_t*)(Hb + (size_t)g * M + c) = o;
    }
}

// ---------------- GCN head aggregation (mu | logstd fused, Z is N x 64) ----------------
// out_i = dis[i] * ( sum_{src->i} dis[src]*Z[src] + dis[i]*Z[i] ) + bias
__global__ __launch_bounds__(TPB) void k_agghead(const float* __restrict__ Z,
                                                 const float* __restrict__ bmu, const float* __restrict__ bls,
                                                 const float* __restrict__ dis,
                                                 const int* __restrict__ rowptr, const int* __restrict__ col,
                                                 float* __restrict__ out, int n) {
    const int GRP = 16;
    int g = blockIdx.x * (TPB / GRP) + threadIdx.x / GRP;
    int l = threadIdx.x & (GRP - 1);
    if (g >= n) return;
    int c = l * 4;
    int r0 = rowptr[g], r1 = rowptr[g + 1];
    float dg = dis[g];
    f4_t acc = dg * (*(const f4_t*)(Z + (size_t)g * 64 + c));
    for (int e = r0; e < r1; ++e) {
        int s = col[e];
        acc += dis[s] * (*(const f4_t*)(Z + (size_t)s * 64 + c));
    }
    f4_t bb = (c < 32) ? *(const f4_t*)(bmu + c) : *(const f4_t*)(bls + (c - 32));
    f4_t o  = dg * acc + bb;
    float* dst = (c < 32) ? (out + (size_t)g * 32 + c)
                          : (out + (size_t)n * 32 + (size_t)g * 32 + (c - 32));
    *(f4_t*)dst = o;
}

// ---------------- launch ----------------

extern "C" void kernel_launch(void* const* d_in, const int* in_sizes, int n_in,
                              void* d_out, int out_size, void* d_ws, size_t ws_size,
                              hipStream_t stream) {
    const float* x   = (const float*)d_in[0];
    const int*   ei  = (const int*)d_in[1];
    const float* W1  = (const float*)d_in[2];
    const float* b1  = (const float*)d_in[3];
    const float* Wr1 = (const float*)d_in[4];
    const float* W2  = (const float*)d_in[5];
    const float* b2  = (const float*)d_in[6];
    const float* Wr2 = (const float*)d_in[7];
    const float* Wmu = (const float*)d_in[8];
    const float* bmu = (const float*)d_in[9];
    const float* Wls = (const float*)d_in[10];
    const float* bls = (const float*)d_in[11];
    float* out = (float*)d_out;

    const int IN = 128, L1F = 96, L2F = 64, OUTF = 32;
    const int N = in_sizes[0] / IN;
    const int E = in_sizes[1] / 2;

    char* ws = (char*)d_ws;
    size_t off = 0;
    auto alloc = [&](size_t b) { size_t r = off; off += (b + 255) & ~(size_t)255; return r; };

    const int nb = (N + TPB - 1) / TPB;
    int*   cnt  = (int*)(ws + alloc((size_t)N * 4));
    int*   bsum = (int*)(ws + alloc((size_t)nb * 4));
    int*   rowp = (int*)(ws + alloc((size_t)(N + 1) * 4));
    int*   curs = (int*)(ws + alloc((size_t)N * 4));
    int*   col  = (int*)(ws + alloc((size_t)E * 4));
    float* dinv = (float*)(ws + alloc((size_t)N * 4));
    float* dis  = (float*)(ws + alloc((size_t)N * 4));
    unsigned short* Xb  = (unsigned short*)(ws + alloc((size_t)N * IN * 2));
    unsigned short* T1  = (unsigned short*)(ws + alloc((size_t)IN  * L1F * 2));
    unsigned short* Tr1 = (unsigned short*)(ws + alloc((size_t)IN  * L1F * 2));
    unsigned short* T2  = (unsigned short*)(ws + alloc((size_t)L1F * L2F * 2));
    unsigned short* Tr2 = (unsigned short*)(ws + alloc((size_t)L1F * L2F * 2));
    unsigned short* Tmu = (unsigned short*)(ws + alloc((size_t)L2F * OUTF * 2));
    unsigned short* Tls = (unsigned short*)(ws + alloc((size_t)L2F * OUTF * 2));
    float* A = (float*)(ws + alloc((size_t)N * 96 * 4));
    float* B = (float*)(ws + alloc((size_t)N * 96 * 4));
    unsigned short* Hb1 = Xb;   // overlay: Xb dead once layer-1 GEMMs complete (N*96*2 <= N*128*2)
    unsigned short* Hb2 = (unsigned short*)(ws + alloc((size_t)N * L2F * 2));

    hipMemsetAsync(cnt, 0, (size_t)N * 4, stream);

    dim3 eg((E + TPB - 1) / TPB);
    k_count<<<eg, TPB, 0, stream>>>(ei, E, cnt);
    k_blocksum<<<nb, TPB, 0, stream>>>(cnt, N, bsum);
    k_scan_bsum<<<1, 512, 0, stream>>>(bsum, nb);
    k_rowptr<<<nb, TPB, 0, stream>>>(cnt, bsum, N, E, rowp, curs, dinv, dis);
    k_fill<<<eg, TPB, 0, stream>>>(ei, E, curs, col);

    long x4 = (long)N * IN / 4;
    k_xconv<<<(unsigned)((x4 + TPB - 1) / TPB), TPB, 0, stream>>>(x, Xb, x4);
    k_wconv<<<dim3(48, 6), TPB, 0, stream>>>(W1, Wr1, W2, Wr2, Wmu, Wls,
                                             T1, Tr1, T2, Tr2, Tmu, Tls);

    const int gb = (N + 63) / 64;
    // layer 1: y1 = x@W1 -> A ; r1 = x@Wr1 -> B ; h1 = relu(dinv*(agg y1) + r1 + b1) -> Hb1 (bf16)
    k_gemm<<<dim3(gb, L1F / 16), TPB, 0, stream>>>(Xb, T1,  A, IN, L1F, 0, N);
    k_gemm<<<dim3(gb, L1F / 16), TPB, 0, stream>>>(Xb, Tr1, B, IN, L1F, 0, N);
    k_aggc<96, 32><<<(N + 7) / 8, TPB, 0, stream>>>(A, B, b1, dinv, rowp, col, Hb1, N);

    // layer 2
    k_gemm<<<dim3(gb, L2F / 16), TPB, 0, stream>>>(Hb1, T2,  A, L1F, L2F, 0, N);
    k_gemm<<<dim3(gb, L2F / 16), TPB, 0, stream>>>(Hb1, Tr2, B, L1F, L2F, 0, N);
    k_aggc<64, 16><<<(N + 15) / 16, TPB, 0, stream>>>(A, B, b2, dinv, rowp, col, Hb2, N);

    // heads: z = h2 @ [Wmu | Wls] -> A (N x 64), then GCN-normalized aggregation -> out
    k_gemm<<<dim3(gb, OUTF / 16), TPB, 0, stream>>>(Hb2, Tmu, A, L2F, 64, 0,  N);
    k_gemm<<<dim3(gb, OUTF / 16), TPB, 0, stream>>>(Hb2, Tls, A, L2F, 64, 32, N);
    k_agghead<<<(N + 15) / 16, TPB, 0, stream>>>(A, bmu, bls, dis, rowp, col, out, N);
}

// Round 2
// 371.321 us; speedup vs baseline: 1.1708x; 1.1708x over previous
//
#include <hip/hip_runtime.h>

#define TPB 256

typedef __attribute__((ext_vector_type(8))) short          bf8_t;   // 8 x bf16 (4 VGPRs)
typedef __attribute__((ext_vector_type(8))) unsigned short us8_t;
typedef __attribute__((ext_vector_type(4))) float          f4_t;
typedef __attribute__((ext_vector_type(4))) unsigned short us4_t;

__device__ __forceinline__ unsigned short f2bf(float f) {
    union { float f; unsigned u; } v; v.f = f;
    unsigned r = v.u + 0x7FFFu + ((v.u >> 16) & 1u);   // round-to-nearest-even
    return (unsigned short)(r >> 16);
}
__device__ __forceinline__ float bf2f(unsigned short u) {
    union { unsigned u; float f; } v; v.u = (unsigned)u << 16; return v.f;
}

// ---------------- graph build (CSR by dst, rebuilt every call) ----------------

__global__ void k_count(const int* __restrict__ ei, int E, int* __restrict__ cnt) {
    int e = blockIdx.x * TPB + threadIdx.x;
    if (e < E) atomicAdd(&cnt[ei[E + e]], 1);
}

__global__ void k_blocksum(const int* __restrict__ cnt, int n, int* __restrict__ bsum) {
    __shared__ int s[TPB];
    int t = threadIdx.x, i = blockIdx.x * TPB + t;
    s[t] = (i < n) ? cnt[i] : 0;
    __syncthreads();
    for (int off = TPB / 2; off > 0; off >>= 1) {
        if (t < off) s[t] += s[t + off];
        __syncthreads();
    }
    if (t == 0) bsum[blockIdx.x] = s[0];
}

__global__ void k_scan_bsum(int* __restrict__ bsum, int nb) {
    __shared__ int s[512];
    int t = threadIdx.x;
    int v = (t < nb) ? bsum[t] : 0;
    s[t] = v; __syncthreads();
    for (int off = 1; off < 512; off <<= 1) {
        int x = (t >= off) ? s[t - off] : 0;
        __syncthreads();
        s[t] += x;
        __syncthreads();
    }
    if (t < nb) bsum[t] = s[t] - v;   // exclusive block offsets
}

__global__ void k_rowptr(const int* __restrict__ cnt, const int* __restrict__ bsum, int n, int E,
                         int* __restrict__ rowptr, int* __restrict__ cursor,
                         float* __restrict__ dinv, float* __restrict__ dis) {
    __shared__ int s[TPB];
    int t = threadIdx.x, i = blockIdx.x * TPB + t;
    int v = (i < n) ? cnt[i] : 0;
    s[t] = v; __syncthreads();
    for (int off = 1; off < TPB; off <<= 1) {
        int x = (t >= off) ? s[t - off] : 0;
        __syncthreads();
        s[t] += x;
        __syncthreads();
    }
    if (i < n) {
        int start = bsum[blockIdx.x] + s[t] - v;
        rowptr[i] = start;
        cursor[i] = start;
        float d = (float)(v + 1);      // + self loop; deg >= 1 always
        dinv[i] = 1.0f / d;
        dis[i]  = rsqrtf(d);
    }
    if (i == 0) rowptr[n] = E;
}

__global__ void k_fill(const int* __restrict__ ei, int E,
                       int* __restrict__ cursor, int* __restrict__ col) {
    int e = blockIdx.x * TPB + threadIdx.x;
    if (e < E) {
        int src = ei[e], dst = ei[E + e];
        int p = atomicAdd(&cursor[dst], 1);
        col[p] = src;
    }
}

// ---------------- conversions ----------------

__global__ void k_xconv(const float* __restrict__ x, unsigned short* __restrict__ xb, long total4) {
    long i = (long)blockIdx.x * TPB + threadIdx.x;
    if (i < total4) {
        f4_t v = *(const f4_t*)(x + i * 4);
        us4_t o;
        o.x = f2bf(v.x); o.y = f2bf(v.y); o.z = f2bf(v.z); o.w = f2bf(v.w);
        *(us4_t*)(xb + i * 4) = o;
    }
}

// transpose+convert all 6 weight matrices: T[m*K + k] = bf16(W[k*M + m])
__global__ void k_wconv(const float* W1, const float* Wr1, const float* W2, const float* Wr2,
                        const float* Wmu, const float* Wls,
                        unsigned short* T1, unsigned short* Tr1, unsigned short* T2,
                        unsigned short* Tr2, unsigned short* Tmu, unsigned short* Tls) {
    const float* W; unsigned short* T; int K, M;
    switch (blockIdx.y) {
        case 0: W = W1;  T = T1;  K = 128; M = 96; break;
        case 1: W = Wr1; T = Tr1; K = 128; M = 96; break;
        case 2: W = W2;  T = T2;  K = 96;  M = 64; break;
        case 3: W = Wr2; T = Tr2; K = 96;  M = 64; break;
        case 4: W = Wmu; T = Tmu; K = 64;  M = 32; break;
        default:W = Wls; T = Tls; K = 64;  M = 32; break;
    }
    int idx = blockIdx.x * TPB + threadIdx.x;
    if (idx < K * M) {
        int m = idx / K, k = idx % K;
        T[idx] = f2bf(W[k * M + m]);
    }
}

// ---------------- bf16 MFMA GEMM: Yb[n][col] = bf16( sum_k Xb[n][k] * W[k][col] ) ----------------
// Xb: n x K bf16 row-major.  WT: M x K bf16 (transposed weight, W||Wr concatenated).
// Yb: n x M bf16. Grid: (M/16, ceil(n/64)) — col-block fastest for A-tile L2 reuse.
// Verified layouts (m89): A-frag m=lane&15,k=quad*8+j ; B same ; C/D col=lane&15,row=quad*4+reg.
__global__ __launch_bounds__(TPB) void k_gemm(const unsigned short* __restrict__ Xb,
                                              const unsigned short* __restrict__ WT,
                                              unsigned short* __restrict__ Yb,
                                              int K, int M, int n) {
    int lane = threadIdx.x & 63;
    int wave = threadIdx.x >> 6;
    int quad = lane >> 4;
    int l15  = lane & 15;
    int base = (blockIdx.y * 4 + wave) * 16;
    int rA = base + l15; if (rA > n - 1) rA = n - 1;
    const unsigned short* ap = Xb + (size_t)rA * K + quad * 8;
    const unsigned short* bp = WT + (size_t)(blockIdx.x * 16 + l15) * K + quad * 8;
    f4_t acc = {0.f, 0.f, 0.f, 0.f};
    for (int k0 = 0; k0 < K; k0 += 32) {
        bf8_t a = *(const bf8_t*)(ap + k0);
        bf8_t b = *(const bf8_t*)(bp + k0);
        acc = __builtin_amdgcn_mfma_f32_16x16x32_bf16(a, b, acc, 0, 0, 0);
    }
    int colg = blockIdx.x * 16 + l15;
    int row  = base + quad * 4;
#pragma unroll
    for (int r = 0; r < 4; r++) {
        if (row + r < n) Yb[(size_t)(row + r) * M + colg] = f2bf(acc[r]);
    }
}

// ---------------- head GEMM: out = Z @ [Wmu|Wls] + bias, fp32, split outputs ----------------
__global__ __launch_bounds__(TPB) void k_gemm_out(const unsigned short* __restrict__ Z,
                                                  const unsigned short* __restrict__ WT,
                                                  const float* __restrict__ bmu,
                                                  const float* __restrict__ bls,
                                                  float* __restrict__ out, int n) {
    int lane = threadIdx.x & 63;
    int wave = threadIdx.x >> 6;
    int quad = lane >> 4;
    int l15  = lane & 15;
    int base = (blockIdx.y * 4 + wave) * 16;
    int rA = base + l15; if (rA > n - 1) rA = n - 1;
    const unsigned short* ap = Z + (size_t)rA * 64 + quad * 8;
    const unsigned short* bp = WT + (size_t)(blockIdx.x * 16 + l15) * 64 + quad * 8;
    f4_t acc = {0.f, 0.f, 0.f, 0.f};
#pragma unroll
    for (int k0 = 0; k0 < 64; k0 += 32) {
        bf8_t a = *(const bf8_t*)(ap + k0);
        bf8_t b = *(const bf8_t*)(bp + k0);
        acc = __builtin_amdgcn_mfma_f32_16x16x32_bf16(a, b, acc, 0, 0, 0);
    }
    int colg = blockIdx.x * 16 + l15;
    float bias = (colg < 32) ? bmu[colg] : bls[colg - 32];
    float* dst = (colg < 32) ? (out + colg) : (out + (size_t)n * 32 + (colg - 32));
    int row = base + quad * 4;
#pragma unroll
    for (int r = 0; r < 4; r++) {
        if (row + r < n) dst[(size_t)(row + r) * 32] = acc[r] + bias;
    }
}

// ---------------- ClusterGCN aggregation (bf16 in/out) ----------------
// AB: n x 2*MF bf16 rows [y | r].  Hb[i] = bf16( s * relu( dinv[i]*(sum_{src->i} y[src] + y[i])
//                                                          + r[i] + bias ) ),  s = SCALE?dis[i]:1
template <int MF, int GRP, bool SCALE>
__global__ __launch_bounds__(TPB) void k_aggc(const unsigned short* __restrict__ AB,
                                              const float* __restrict__ bias,
                                              const float* __restrict__ dinv,
                                              const float* __restrict__ dis,
                                              const int* __restrict__ rowptr,
                                              const int* __restrict__ col,
                                              unsigned short* __restrict__ Hb, int n) {
    constexpr int LD = 2 * MF;
    int g = blockIdx.x * (TPB / GRP) + threadIdx.x / GRP;
    int l = threadIdx.x & (GRP - 1);
    if (g >= n) return;
    int c = l * 8;
    if (c >= MF) return;
    int r0 = rowptr[g], r1 = rowptr[g + 1];
    float acc[8];
    {
        bf8_t v = *(const bf8_t*)(AB + (size_t)g * LD + c);
#pragma unroll
        for (int j = 0; j < 8; j++) acc[j] = bf2f((unsigned short)v[j]);
    }
    int e = r0;
    for (; e + 4 <= r1; e += 4) {          // 4-way MLP unroll
        int s0 = col[e], s1 = col[e + 1], s2 = col[e + 2], s3 = col[e + 3];
        bf8_t v0 = *(const bf8_t*)(AB + (size_t)s0 * LD + c);
        bf8_t v1 = *(const bf8_t*)(AB + (size_t)s1 * LD + c);
        bf8_t v2 = *(const bf8_t*)(AB + (size_t)s2 * LD + c);
        bf8_t v3 = *(const bf8_t*)(AB + (size_t)s3 * LD + c);
#pragma unroll
        for (int j = 0; j < 8; j++)
            acc[j] += (bf2f((unsigned short)v0[j]) + bf2f((unsigned short)v1[j]))
                    + (bf2f((unsigned short)v2[j]) + bf2f((unsigned short)v3[j]));
    }
    for (; e < r1; ++e) {
        int s = col[e];
        bf8_t v = *(const bf8_t*)(AB + (size_t)s * LD + c);
#pragma unroll
        for (int j = 0; j < 8; j++) acc[j] += bf2f((unsigned short)v[j]);
    }
    float di = dinv[g];
    float sc = SCALE ? dis[g] : 1.0f;
    bf8_t rr = *(const bf8_t*)(AB + (size_t)g * LD + MF + c);
    us8_t o;
#pragma unroll
    for (int j = 0; j < 8; j++) {
        float h = fmaxf(acc[j] * di + bf2f((unsigned short)rr[j]) + bias[c + j], 0.f);
        o[j] = f2bf(SCALE ? sc * h : h);
    }
    *(us8_t*)(Hb + (size_t)g * MF + c) = o;
}

// ---------------- head aggregation: Z[g] = bf16( dis[g] * (sum_{src->g} H2s[src] + H2s[g]) ) ----
// H2s rows are pre-scaled by dis (written by layer-2 epilogue), so no per-edge dis load.
__global__ __launch_bounds__(TPB) void k_agghead(const unsigned short* __restrict__ H2s,
                                                 const float* __restrict__ dis,
                                                 const int* __restrict__ rowptr,
                                                 const int* __restrict__ col,
                                                 unsigned short* __restrict__ Z, int n) {
    const int GRP = 8;
    int g = blockIdx.x * (TPB / GRP) + threadIdx.x / GRP;
    int l = threadIdx.x & (GRP - 1);
    if (g >= n) return;
    int c = l * 8;
    int r0 = rowptr[g], r1 = rowptr[g + 1];
    float acc[8];
    {
        bf8_t v = *(const bf8_t*)(H2s + (size_t)g * 64 + c);
#pragma unroll
        for (int j = 0; j < 8; j++) acc[j] = bf2f((unsigned short)v[j]);
    }
    int e = r0;
    for (; e + 4 <= r1; e += 4) {
        int s0 = col[e], s1 = col[e + 1], s2 = col[e + 2], s3 = col[e + 3];
        bf8_t v0 = *(const bf8_t*)(H2s + (size_t)s0 * 64 + c);
        bf8_t v1 = *(const bf8_t*)(H2s + (size_t)s1 * 64 + c);
        bf8_t v2 = *(const bf8_t*)(H2s + (size_t)s2 * 64 + c);
        bf8_t v3 = *(const bf8_t*)(H2s + (size_t)s3 * 64 + c);
#pragma unroll
        for (int j = 0; j < 8; j++)
            acc[j] += (bf2f((unsigned short)v0[j]) + bf2f((unsigned short)v1[j]))
                    + (bf2f((unsigned short)v2[j]) + bf2f((unsigned short)v3[j]));
    }
    for (; e < r1; ++e) {
        int s = col[e];
        bf8_t v = *(const bf8_t*)(H2s + (size_t)s * 64 + c);
#pragma unroll
        for (int j = 0; j < 8; j++) acc[j] += bf2f((unsigned short)v[j]);
    }
    float dg = dis[g];
    us8_t o;
#pragma unroll
    for (int j = 0; j < 8; j++) o[j] = f2bf(dg * acc[j]);
    *(us8_t*)(Z + (size_t)g * 64 + c) = o;
}

// ---------------- launch ----------------

extern "C" void kernel_launch(void* const* d_in, const int* in_sizes, int n_in,
                              void* d_out, int out_size, void* d_ws, size_t ws_size,
                              hipStream_t stream) {
    const float* x   = (const float*)d_in[0];
    const int*   ei  = (const int*)d_in[1];
    const float* W1  = (const float*)d_in[2];
    const float* b1  = (const float*)d_in[3];
    const float* Wr1 = (const float*)d_in[4];
    const float* W2  = (const float*)d_in[5];
    const float* b2  = (const float*)d_in[6];
    const float* Wr2 = (const float*)d_in[7];
    const float* Wmu = (const float*)d_in[8];
    const float* bmu = (const float*)d_in[9];
    const float* Wls = (const float*)d_in[10];
    const float* bls = (const float*)d_in[11];
    float* out = (float*)d_out;

    const int IN = 128, L1F = 96, L2F = 64;
    const int N = in_sizes[0] / IN;
    const int E = in_sizes[1] / 2;

    char* ws = (char*)d_ws;
    size_t off = 0;
    auto alloc = [&](size_t b) { size_t r = off; off += (b + 255) & ~(size_t)255; return r; };

    const int nb = (N + TPB - 1) / TPB;
    int*   cnt  = (int*)(ws + alloc((size_t)N * 4));
    int*   bsum = (int*)(ws + alloc((size_t)nb * 4));
    int*   rowp = (int*)(ws + alloc((size_t)(N + 1) * 4));
    int*   curs = (int*)(ws + alloc((size_t)N * 4));
    int*   col  = (int*)(ws + alloc((size_t)E * 4));
    float* dinv = (float*)(ws + alloc((size_t)N * 4));
    float* dis  = (float*)(ws + alloc((size_t)N * 4));
    unsigned short* Xb  = (unsigned short*)(ws + alloc((size_t)N * IN * 2));
    // weight blocks allocated contiguously -> concatenated [W|Wr] views (all sizes %256==0)
    unsigned short* T1  = (unsigned short*)(ws + alloc((size_t)IN  * L1F * 2));
    unsigned short* Tr1 = (unsigned short*)(ws + alloc((size_t)IN  * L1F * 2));
    unsigned short* T2  = (unsigned short*)(ws + alloc((size_t)L1F * L2F * 2));
    unsigned short* Tr2 = (unsigned short*)(ws + alloc((size_t)L1F * L2F * 2));
    unsigned short* Tmu = (unsigned short*)(ws + alloc((size_t)L2F * 32 * 2));
    unsigned short* Tls = (unsigned short*)(ws + alloc((size_t)L2F * 32 * 2));
    unsigned short* AB1 = (unsigned short*)(ws + alloc((size_t)N * 2 * L1F * 2)); // N x 192 bf16
    unsigned short* AB2 = (unsigned short*)(ws + alloc((size_t)N * 2 * L2F * 2)); // N x 128 bf16
    unsigned short* H2s = (unsigned short*)(ws + alloc((size_t)N * L2F * 2));     // dis-scaled h2
    unsigned short* Zag = (unsigned short*)(ws + alloc((size_t)N * L2F * 2));     // aggregated head input
    unsigned short* Hb1 = Xb;   // overlay: Xb dead after layer-1 GEMM (N*96*2 <= N*128*2)

    hipMemsetAsync(cnt, 0, (size_t)N * 4, stream);

    dim3 eg((E + TPB - 1) / TPB);
    k_count<<<eg, TPB, 0, stream>>>(ei, E, cnt);
    k_blocksum<<<nb, TPB, 0, stream>>>(cnt, N, bsum);
    k_scan_bsum<<<1, 512, 0, stream>>>(bsum, nb);
    k_rowptr<<<nb, TPB, 0, stream>>>(cnt, bsum, N, E, rowp, curs, dinv, dis);
    k_fill<<<eg, TPB, 0, stream>>>(ei, E, curs, col);

    long x4 = (long)N * IN / 4;
    k_xconv<<<(unsigned)((x4 + TPB - 1) / TPB), TPB, 0, stream>>>(x, Xb, x4);
    k_wconv<<<dim3(48, 6), TPB, 0, stream>>>(W1, Wr1, W2, Wr2, Wmu, Wls,
                                             T1, Tr1, T2, Tr2, Tmu, Tls);

    const int gb = (N + 63) / 64;
    // layer 1: AB1 = x @ [W1|Wr1] (bf16), Hb1 = relu(dinv*agg(y) + r + b1)
    k_gemm<<<dim3(12, gb), TPB, 0, stream>>>(Xb, T1, AB1, IN, 2 * L1F, N);
    k_aggc<96, 16, false><<<(N + 15) / 16, TPB, 0, stream>>>(AB1, b1, dinv, dis, rowp, col, Hb1, N);

    // layer 2: AB2 = h1 @ [W2|Wr2], H2s = dis * relu(dinv*agg(y) + r + b2)
    k_gemm<<<dim3(8, gb), TPB, 0, stream>>>(Hb1, T2, AB2, L1F, 2 * L2F, N);
    k_aggc<64, 8, true><<<(N + 31) / 32, TPB, 0, stream>>>(AB2, b2, dinv, dis, rowp, col, H2s, N);

    // heads: Zag = dis * (agg H2s + H2s), out = Zag @ [Wmu|Wls] + bias
    k_agghead<<<(N + 31) / 32, TPB, 0, stream>>>(H2s, dis, rowp, col, Zag, N);
    k_gemm_out<<<dim3(4, gb), TPB, 0, stream>>>(Zag, Tmu, bmu, bls, out, N);
}

// Round 3
// 317.301 us; speedup vs baseline: 1.3701x; 1.1702x over previous
//
#include <hip/hip_runtime.h>

#define TPB 256

typedef __attribute__((ext_vector_type(8))) short          bf8_t;   // 8 x bf16 (4 VGPRs)
typedef __attribute__((ext_vector_type(8))) unsigned short us8_t;
typedef __attribute__((ext_vector_type(4))) float          f4_t;
typedef __attribute__((ext_vector_type(4))) unsigned short us4_t;

__device__ __forceinline__ unsigned short f2bf(float f) {
    union { float f; unsigned u; } v; v.f = f;
    unsigned r = v.u + 0x7FFFu + ((v.u >> 16) & 1u);   // round-to-nearest-even
    return (unsigned short)(r >> 16);
}
__device__ __forceinline__ float bf2f(unsigned short u) {
    union { unsigned u; float f; } v; v.u = (unsigned)u << 16; return v.f;
}

// ---------------- graph build (CSR by dst, rebuilt every call) ----------------

__global__ void k_count(const int* __restrict__ ei, int E, int* __restrict__ cnt) {
    int e = blockIdx.x * TPB + threadIdx.x;
    if (e < E) atomicAdd(&cnt[ei[E + e]], 1);
}

__global__ void k_blocksum(const int* __restrict__ cnt, int n, int* __restrict__ bsum) {
    __shared__ int s[TPB];
    int t = threadIdx.x, i = blockIdx.x * TPB + t;
    s[t] = (i < n) ? cnt[i] : 0;
    __syncthreads();
    for (int off = TPB / 2; off > 0; off >>= 1) {
        if (t < off) s[t] += s[t + off];
        __syncthreads();
    }
    if (t == 0) bsum[blockIdx.x] = s[0];
}

__global__ void k_scan_bsum(int* __restrict__ bsum, int nb) {
    __shared__ int s[512];
    int t = threadIdx.x;
    int v = (t < nb) ? bsum[t] : 0;
    s[t] = v; __syncthreads();
    for (int off = 1; off < 512; off <<= 1) {
        int x = (t >= off) ? s[t - off] : 0;
        __syncthreads();
        s[t] += x;
        __syncthreads();
    }
    if (t < nb) bsum[t] = s[t] - v;   // exclusive block offsets
}

__global__ void k_rowptr(const int* __restrict__ cnt, const int* __restrict__ bsum, int n, int E,
                         int* __restrict__ rowptr, int* __restrict__ cursor,
                         float* __restrict__ dinv, float* __restrict__ dis) {
    __shared__ int s[TPB];
    int t = threadIdx.x, i = blockIdx.x * TPB + t;
    int v = (i < n) ? cnt[i] : 0;
    s[t] = v; __syncthreads();
    for (int off = 1; off < TPB; off <<= 1) {
        int x = (t >= off) ? s[t - off] : 0;
        __syncthreads();
        s[t] += x;
        __syncthreads();
    }
    if (i < n) {
        int start = bsum[blockIdx.x] + s[t] - v;
        rowptr[i] = start;
        cursor[i] = start;
        float d = (float)(v + 1);      // + self loop; deg >= 1 always
        dinv[i] = 1.0f / d;
        dis[i]  = rsqrtf(d);
    }
    if (i == 0) rowptr[n] = E;
}

__global__ void k_fill(const int* __restrict__ ei, int E,
                       int* __restrict__ cursor, int* __restrict__ col) {
    int e = blockIdx.x * TPB + threadIdx.x;
    if (e < E) {
        int src = ei[e], dst = ei[E + e];
        int p = atomicAdd(&cursor[dst], 1);
        col[p] = src;
    }
}

// ---------------- weight transpose+convert: T[m*K + k] = bf16(W[k*M + m]) ----------------
__global__ void k_wconv(const float* W1, const float* Wr1, const float* W2, const float* Wr2,
                        const float* Wmu, const float* Wls,
                        unsigned short* T1, unsigned short* Tr1, unsigned short* T2,
                        unsigned short* Tr2, unsigned short* Tmu, unsigned short* Tls) {
    const float* W; unsigned short* T; int K, M;
    switch (blockIdx.y) {
        case 0: W = W1;  T = T1;  K = 128; M = 96; break;
        case 1: W = Wr1; T = Tr1; K = 128; M = 96; break;
        case 2: W = W2;  T = T2;  K = 96;  M = 64; break;
        case 3: W = Wr2; T = Tr2; K = 96;  M = 64; break;
        case 4: W = Wmu; T = Tmu; K = 64;  M = 32; break;
        default:W = Wls; T = Tls; K = 64;  M = 32; break;
    }
    int idx = blockIdx.x * TPB + threadIdx.x;
    if (idx < K * M) {
        int m = idx / K, k = idx % K;
        T[idx] = f2bf(W[k * M + m]);
    }
}

// ---------------- MFMA GEMM, A-resident: one block = 64 rows, loops all M/16 col tiles -------
// A: n x K (fp32 if AF32 else bf16).  WT: M x K bf16.  Yb: n x M bf16.
// A-frags loaded ONCE into registers -> A fetched exactly once from HBM (no XCD L2 overfetch).
// Verified layouts (m89): A-frag m=lane&15,k=quad*8+j ; B same ; C/D col=lane&15,row=quad*4+reg.
template <int K, int M, bool AF32>
__global__ __launch_bounds__(TPB) void k_gemm2(const void* __restrict__ Av,
                                               const unsigned short* __restrict__ WT,
                                               unsigned short* __restrict__ Yb, int n) {
    constexpr int KS = K / 32;
    int lane = threadIdx.x & 63;
    int wave = threadIdx.x >> 6;
    int quad = lane >> 4;
    int l15  = lane & 15;
    int base = (blockIdx.x * 4 + wave) * 16;
    int rA = base + l15; if (rA > n - 1) rA = n - 1;

    bf8_t a[KS];
    if (AF32) {
        const float* ap = (const float*)Av + (size_t)rA * K + quad * 8;
#pragma unroll
        for (int s = 0; s < KS; s++) {
            f4_t lo = *(const f4_t*)(ap + s * 32);
            f4_t hi = *(const f4_t*)(ap + s * 32 + 4);
            bf8_t t;
            t[0] = (short)f2bf(lo.x); t[1] = (short)f2bf(lo.y);
            t[2] = (short)f2bf(lo.z); t[3] = (short)f2bf(lo.w);
            t[4] = (short)f2bf(hi.x); t[5] = (short)f2bf(hi.y);
            t[6] = (short)f2bf(hi.z); t[7] = (short)f2bf(hi.w);
            a[s] = t;
        }
    } else {
        const unsigned short* ap = (const unsigned short*)Av + (size_t)rA * K + quad * 8;
#pragma unroll
        for (int s = 0; s < KS; s++) a[s] = *(const bf8_t*)(ap + s * 32);
    }

    int row = base + quad * 4;
#pragma unroll
    for (int ct = 0; ct < M / 16; ct++) {
        const unsigned short* bp = WT + (size_t)(ct * 16 + l15) * K + quad * 8;
        f4_t acc = {0.f, 0.f, 0.f, 0.f};
#pragma unroll
        for (int s = 0; s < KS; s++) {
            bf8_t b = *(const bf8_t*)(bp + s * 32);
            acc = __builtin_amdgcn_mfma_f32_16x16x32_bf16(a[s], b, acc, 0, 0, 0);
        }
        int colg = ct * 16 + l15;
#pragma unroll
        for (int r = 0; r < 4; r++) {
            if (row + r < n) Yb[(size_t)(row + r) * M + colg] = f2bf(acc[r]);
        }
    }
}

// ---------------- head GEMM: out = Z @ [Wmu|Wls] + bias, fp32, split outputs ----------------
__global__ __launch_bounds__(TPB) void k_gemm_out(const unsigned short* __restrict__ Z,
                                                  const unsigned short* __restrict__ WT,
                                                  const float* __restrict__ bmu,
                                                  const float* __restrict__ bls,
                                                  float* __restrict__ out, int n) {
    int lane = threadIdx.x & 63;
    int wave = threadIdx.x >> 6;
    int quad = lane >> 4;
    int l15  = lane & 15;
    int base = (blockIdx.x * 4 + wave) * 16;
    int rA = base + l15; if (rA > n - 1) rA = n - 1;
    const unsigned short* ap = Z + (size_t)rA * 64 + quad * 8;
    bf8_t a0 = *(const bf8_t*)(ap);
    bf8_t a1 = *(const bf8_t*)(ap + 32);
    int row = base + quad * 4;
#pragma unroll
    for (int ct = 0; ct < 4; ct++) {
        const unsigned short* bp = WT + (size_t)(ct * 16 + l15) * 64 + quad * 8;
        f4_t acc = {0.f, 0.f, 0.f, 0.f};
        acc = __builtin_amdgcn_mfma_f32_16x16x32_bf16(a0, *(const bf8_t*)bp, acc, 0, 0, 0);
        acc = __builtin_amdgcn_mfma_f32_16x16x32_bf16(a1, *(const bf8_t*)(bp + 32), acc, 0, 0, 0);
        int colg = ct * 16 + l15;
        float bias = (colg < 32) ? bmu[colg] : bls[colg - 32];
        float* dst = (colg < 32) ? (out + colg) : (out + (size_t)n * 32 + (colg - 32));
#pragma unroll
        for (int r = 0; r < 4; r++) {
            if (row + r < n) dst[(size_t)(row + r) * 32] = acc[r] + bias;
        }
    }
}

// ---------------- ClusterGCN aggregation (bf16 in/out) ----------------
// AB: n x 2*MF bf16 rows [y | r].  Hb[i] = bf16( s * relu( dinv[i]*(sum_{src->i} y[src] + y[i])
//                                                          + r[i] + bias ) ),  s = SCALE?dis[i]:1
template <int MF, int GRP, bool SCALE>
__global__ __launch_bounds__(TPB) void k_aggc(const unsigned short* __restrict__ AB,
                                              const float* __restrict__ bias,
                                              const float* __restrict__ dinv,
                                              const float* __restrict__ dis,
                                              const int* __restrict__ rowptr,
                                              const int* __restrict__ col,
                                              unsigned short* __restrict__ Hb, int n) {
    constexpr int LD = 2 * MF;
    int g = blockIdx.x * (TPB / GRP) + threadIdx.x / GRP;
    int l = threadIdx.x & (GRP - 1);
    if (g >= n) return;
    int c = l * 8;
    if (c >= MF) return;
    int r0 = rowptr[g], r1 = rowptr[g + 1];
    float acc[8];
    {
        bf8_t v = *(const bf8_t*)(AB + (size_t)g * LD + c);
#pragma unroll
        for (int j = 0; j < 8; j++) acc[j] = bf2f((unsigned short)v[j]);
    }
    int e = r0;
    for (; e + 4 <= r1; e += 4) {          // 4-way MLP unroll
        int s0 = col[e], s1 = col[e + 1], s2 = col[e + 2], s3 = col[e + 3];
        bf8_t v0 = *(const bf8_t*)(AB + (size_t)s0 * LD + c);
        bf8_t v1 = *(const bf8_t*)(AB + (size_t)s1 * LD + c);
        bf8_t v2 = *(const bf8_t*)(AB + (size_t)s2 * LD + c);
        bf8_t v3 = *(const bf8_t*)(AB + (size_t)s3 * LD + c);
#pragma unroll
        for (int j = 0; j < 8; j++)
            acc[j] += (bf2f((unsigned short)v0[j]) + bf2f((unsigned short)v1[j]))
                    + (bf2f((unsigned short)v2[j]) + bf2f((unsigned short)v3[j]));
    }
    for (; e < r1; ++e) {
        int s = col[e];
        bf8_t v = *(const bf8_t*)(AB + (size_t)s * LD + c);
#pragma unroll
        for (int j = 0; j < 8; j++) acc[j] += bf2f((unsigned short)v[j]);
    }
    float di = dinv[g];
    float sc = SCALE ? dis[g] : 1.0f;
    bf8_t rr = *(const bf8_t*)(AB + (size_t)g * LD + MF + c);
    us8_t o;
#pragma unroll
    for (int j = 0; j < 8; j++) {
        float h = fmaxf(acc[j] * di + bf2f((unsigned short)rr[j]) + bias[c + j], 0.f);
        o[j] = f2bf(SCALE ? sc * h : h);
    }
    *(us8_t*)(Hb + (size_t)g * MF + c) = o;
}

// ---------------- head aggregation: Z[g] = bf16( dis[g] * (sum_{src->g} H2s[src] + H2s[g]) ) ----
// H2s rows are pre-scaled by dis (written by layer-2 epilogue), so no per-edge dis load.
__global__ __launch_bounds__(TPB) void k_agghead(const unsigned short* __restrict__ H2s,
                                                 const float* __restrict__ dis,
                                                 const int* __restrict__ rowptr,
                                                 const int* __restrict__ col,
                                                 unsigned short* __restrict__ Z, int n) {
    const int GRP = 8;
    int g = blockIdx.x * (TPB / GRP) + threadIdx.x / GRP;
    int l = threadIdx.x & (GRP - 1);
    if (g >= n) return;
    int c = l * 8;
    int r0 = rowptr[g], r1 = rowptr[g + 1];
    float acc[8];
    {
        bf8_t v = *(const bf8_t*)(H2s + (size_t)g * 64 + c);
#pragma unroll
        for (int j = 0; j < 8; j++) acc[j] = bf2f((unsigned short)v[j]);
    }
    int e = r0;
    for (; e + 4 <= r1; e += 4) {
        int s0 = col[e], s1 = col[e + 1], s2 = col[e + 2], s3 = col[e + 3];
        bf8_t v0 = *(const bf8_t*)(H2s + (size_t)s0 * 64 + c);
        bf8_t v1 = *(const bf8_t*)(H2s + (size_t)s1 * 64 + c);
        bf8_t v2 = *(const bf8_t*)(H2s + (size_t)s2 * 64 + c);
        bf8_t v3 = *(const bf8_t*)(H2s + (size_t)s3 * 64 + c);
#pragma unroll
        for (int j = 0; j < 8; j++)
            acc[j] += (bf2f((unsigned short)v0[j]) + bf2f((unsigned short)v1[j]))
                    + (bf2f((unsigned short)v2[j]) + bf2f((unsigned short)v3[j]));
    }
    for (; e < r1; ++e) {
        int s = col[e];
        bf8_t v = *(const bf8_t*)(H2s + (size_t)s * 64 + c);
#pragma unroll
        for (int j = 0; j < 8; j++) acc[j] += bf2f((unsigned short)v[j]);
    }
    float dg = dis[g];
    us8_t o;
#pragma unroll
    for (int j = 0; j < 8; j++) o[j] = f2bf(dg * acc[j]);
    *(us8_t*)(Z + (size_t)g * 64 + c) = o;
}

// ---------------- launch ----------------

extern "C" void kernel_launch(void* const* d_in, const int* in_sizes, int n_in,
                              void* d_out, int out_size, void* d_ws, size_t ws_size,
                              hipStream_t stream) {
    const float* x   = (const float*)d_in[0];
    const int*   ei  = (const int*)d_in[1];
    const float* W1  = (const float*)d_in[2];
    const float* b1  = (const float*)d_in[3];
    const float* Wr1 = (const float*)d_in[4];
    const float* W2  = (const float*)d_in[5];
    const float* b2  = (const float*)d_in[6];
    const float* Wr2 = (const float*)d_in[7];
    const float* Wmu = (const float*)d_in[8];
    const float* bmu = (const float*)d_in[9];
    const float* Wls = (const float*)d_in[10];
    const float* bls = (const float*)d_in[11];
    float* out = (float*)d_out;

    const int IN = 128, L1F = 96, L2F = 64;
    const int N = in_sizes[0] / IN;
    const int E = in_sizes[1] / 2;

    char* ws = (char*)d_ws;
    size_t off = 0;
    auto alloc = [&](size_t b) { size_t r = off; off += (b + 255) & ~(size_t)255; return r; };

    const int nb = (N + TPB - 1) / TPB;
    int*   cnt  = (int*)(ws + alloc((size_t)N * 4));
    int*   bsum = (int*)(ws + alloc((size_t)nb * 4));
    int*   rowp = (int*)(ws + alloc((size_t)(N + 1) * 4));
    int*   curs = (int*)(ws + alloc((size_t)N * 4));
    int*   col  = (int*)(ws + alloc((size_t)E * 4));
    float* dinv = (float*)(ws + alloc((size_t)N * 4));
    float* dis  = (float*)(ws + alloc((size_t)N * 4));
    // weight blocks allocated contiguously -> concatenated [W|Wr] views (all sizes %256==0)
    unsigned short* T1  = (unsigned short*)(ws + alloc((size_t)IN  * L1F * 2));
    unsigned short* Tr1 = (unsigned short*)(ws + alloc((size_t)IN  * L1F * 2));
    unsigned short* T2  = (unsigned short*)(ws + alloc((size_t)L1F * L2F * 2));
    unsigned short* Tr2 = (unsigned short*)(ws + alloc((size_t)L1F * L2F * 2));
    unsigned short* Tmu = (unsigned short*)(ws + alloc((size_t)L2F * 32 * 2));
    unsigned short* Tls = (unsigned short*)(ws + alloc((size_t)L2F * 32 * 2));
    unsigned short* AB1 = (unsigned short*)(ws + alloc((size_t)N * 2 * L1F * 2)); // N x 192 bf16
    unsigned short* AB2 = (unsigned short*)(ws + alloc((size_t)N * 2 * L2F * 2)); // N x 128 bf16
    unsigned short* Hb1 = (unsigned short*)(ws + alloc((size_t)N * L1F * 2));     // relu'd h1
    unsigned short* H2s = (unsigned short*)(ws + alloc((size_t)N * L2F * 2));     // dis-scaled h2
    unsigned short* Zag = (unsigned short*)(ws + alloc((size_t)N * L2F * 2));     // aggregated head input

    hipMemsetAsync(cnt, 0, (size_t)N * 4, stream);

    dim3 eg((E + TPB - 1) / TPB);
    k_count<<<eg, TPB, 0, stream>>>(ei, E, cnt);
    k_blocksum<<<nb, TPB, 0, stream>>>(cnt, N, bsum);
    k_scan_bsum<<<1, 512, 0, stream>>>(bsum, nb);
    k_rowptr<<<nb, TPB, 0, stream>>>(cnt, bsum, N, E, rowp, curs, dinv, dis);
    k_fill<<<eg, TPB, 0, stream>>>(ei, E, curs, col);

    k_wconv<<<dim3(48, 6), TPB, 0, stream>>>(W1, Wr1, W2, Wr2, Wmu, Wls,
                                             T1, Tr1, T2, Tr2, Tmu, Tls);

    const int gb = (N + 63) / 64;
    // layer 1: AB1 = x @ [W1|Wr1] (fused fp32->bf16 on A), Hb1 = relu(dinv*agg(y) + r + b1)
    k_gemm2<128, 192, true><<<gb, TPB, 0, stream>>>(x, T1, AB1, N);
    k_aggc<96, 16, false><<<(N + 15) / 16, TPB, 0, stream>>>(AB1, b1, dinv, dis, rowp, col, Hb1, N);

    // layer 2: AB2 = h1 @ [W2|Wr2], H2s = dis * relu(dinv*agg(y) + r + b2)
    k_gemm2<96, 128, false><<<gb, TPB, 0, stream>>>(Hb1, T2, AB2, N);
    k_aggc<64, 8, true><<<(N + 31) / 32, TPB, 0, stream>>>(AB2, b2, dinv, dis, rowp, col, H2s, N);

    // heads: Zag = dis * (agg H2s + H2s), out = Zag @ [Wmu|Wls] + bias
    k_agghead<<<(N + 31) / 32, TPB, 0, stream>>>(H2s, dis, rowp, col, Zag, N);
    k_gemm_out<<<gb, TPB, 0, stream>>>(Zag, Tmu, bmu, bls, out, N);
}

// Round 4
// 291.987 us; speedup vs baseline: 1.4889x; 1.0867x over previous
//
#include <hip/hip_runtime.h>

#define TPB 256

typedef __attribute__((ext_vector_type(8))) short          bf8_t;   // 8 x bf16 (4 VGPRs)
typedef __attribute__((ext_vector_type(8))) unsigned short us8_t;
typedef __attribute__((ext_vector_type(4))) float          f4_t;
typedef __attribute__((ext_vector_type(4))) unsigned short us4_t;

__device__ __forceinline__ unsigned short f2bf(float f) {
    union { float f; unsigned u; } v; v.f = f;
    unsigned r = v.u + 0x7FFFu + ((v.u >> 16) & 1u);   // round-to-nearest-even
    return (unsigned short)(r >> 16);
}
__device__ __forceinline__ float bf2f(unsigned short u) {
    union { unsigned u; float f; } v; v.u = (unsigned)u << 16; return v.f;
}

// ---------------- graph build (CSR by dst, rebuilt every call) ----------------

__global__ void k_count(const int* __restrict__ ei, int E, int* __restrict__ cnt) {
    int e = blockIdx.x * TPB + threadIdx.x;
    if (e < E) atomicAdd(&cnt[ei[E + e]], 1);
}

__global__ void k_blocksum(const int* __restrict__ cnt, int n, int* __restrict__ bsum) {
    __shared__ int s[TPB];
    int t = threadIdx.x, i = blockIdx.x * TPB + t;
    s[t] = (i < n) ? cnt[i] : 0;
    __syncthreads();
    for (int off = TPB / 2; off > 0; off >>= 1) {
        if (t < off) s[t] += s[t + off];
        __syncthreads();
    }
    if (t == 0) bsum[blockIdx.x] = s[0];
}

__global__ void k_scan_bsum(int* __restrict__ bsum, int nb) {
    __shared__ int s[512];
    int t = threadIdx.x;
    int v = (t < nb) ? bsum[t] : 0;
    s[t] = v; __syncthreads();
    for (int off = 1; off < 512; off <<= 1) {
        int x = (t >= off) ? s[t - off] : 0;
        __syncthreads();
        s[t] += x;
        __syncthreads();
    }
    if (t < nb) bsum[t] = s[t] - v;   // exclusive block offsets
}

__global__ void k_rowptr(const int* __restrict__ cnt, const int* __restrict__ bsum, int n, int E,
                         int* __restrict__ rowptr, int* __restrict__ cursor,
                         float* __restrict__ dinv, float* __restrict__ dis) {
    __shared__ int s[TPB];
    int t = threadIdx.x, i = blockIdx.x * TPB + t;
    int v = (i < n) ? cnt[i] : 0;
    s[t] = v; __syncthreads();
    for (int off = 1; off < TPB; off <<= 1) {
        int x = (t >= off) ? s[t - off] : 0;
        __syncthreads();
        s[t] += x;
        __syncthreads();
    }
    if (i < n) {
        int start = bsum[blockIdx.x] + s[t] - v;
        rowptr[i] = start;
        cursor[i] = start;
        float d = (float)(v + 1);      // + self loop; deg >= 1 always
        dinv[i] = 1.0f / d;
        dis[i]  = rsqrtf(d);
    }
    if (i == 0) rowptr[n] = E;
}

__global__ void k_fill(const int* __restrict__ ei, int E,
                       int* __restrict__ cursor, int* __restrict__ col) {
    int e = blockIdx.x * TPB + threadIdx.x;
    if (e < E) {
        int src = ei[e], dst = ei[E + e];
        int p = atomicAdd(&cursor[dst], 1);
        col[p] = src;
    }
}

// ---------------- weight transpose+convert: T[m*K + k] = bf16(W[k*M + m]) ----------------
__global__ void k_wconv(const float* W1, const float* Wr1, const float* W2, const float* Wr2,
                        const float* Wmu, const float* Wls,
                        unsigned short* T1, unsigned short* Tr1, unsigned short* T2,
                        unsigned short* Tr2, unsigned short* Tmu, unsigned short* Tls) {
    const float* W; unsigned short* T; int K, M;
    switch (blockIdx.y) {
        case 0: W = W1;  T = T1;  K = 128; M = 96; break;
        case 1: W = Wr1; T = Tr1; K = 128; M = 96; break;
        case 2: W = W2;  T = T2;  K = 96;  M = 64; break;
        case 3: W = Wr2; T = Tr2; K = 96;  M = 64; break;
        case 4: W = Wmu; T = Tmu; K = 64;  M = 32; break;
        default:W = Wls; T = Tls; K = 64;  M = 32; break;
    }
    int idx = blockIdx.x * TPB + threadIdx.x;
    if (idx < K * M) {
        int m = idx / K, k = idx % K;
        T[idx] = f2bf(W[k * M + m]);
    }
}

// ---------------- MFMA GEMM v3: LDS-staged B, grid-stride row tiles ----------------
// A: n x K (fp32 if AF32 else bf16).  WT: M x K bf16.  Yb: n x M bf16.
// B staged once per block into LDS with padded stride ST=K+8 (272/208/144 B rows):
// l15 lanes spread across all 32 banks, only 2-way aliasing (free, m136); 16B-aligned.
// Grid-stride over 64-row tiles; ct loop fully unrolled -> 12 independent MFMA chains.
template <int K, int M, bool AF32>
__global__ __launch_bounds__(TPB) void k_gemm3(const void* __restrict__ Av,
                                               const unsigned short* __restrict__ WT,
                                               unsigned short* __restrict__ Yb,
                                               int n, int nt) {
    constexpr int KS = K / 32;
    constexpr int ST = K + 8;
    __shared__ unsigned short Bs[M * ST];
    for (int i = threadIdx.x * 8; i < M * K; i += TPB * 8) {
        int m = i / K, k = i - m * K;
        *(us8_t*)(Bs + m * ST + k) = *(const us8_t*)(WT + i);
    }
    __syncthreads();

    int lane = threadIdx.x & 63;
    int wave = threadIdx.x >> 6;
    int quad = lane >> 4;
    int l15  = lane & 15;

    for (int tile = blockIdx.x; tile < nt; tile += gridDim.x) {
        int base = tile * 64 + wave * 16;
        int rA = base + l15; if (rA > n - 1) rA = n - 1;

        bf8_t a[KS];
        if (AF32) {
            const float* ap = (const float*)Av + (size_t)rA * K + quad * 8;
#pragma unroll
            for (int s = 0; s < KS; s++) {
                f4_t lo = *(const f4_t*)(ap + s * 32);
                f4_t hi = *(const f4_t*)(ap + s * 32 + 4);
                bf8_t t;
                t[0] = (short)f2bf(lo.x); t[1] = (short)f2bf(lo.y);
                t[2] = (short)f2bf(lo.z); t[3] = (short)f2bf(lo.w);
                t[4] = (short)f2bf(hi.x); t[5] = (short)f2bf(hi.y);
                t[6] = (short)f2bf(hi.z); t[7] = (short)f2bf(hi.w);
                a[s] = t;
            }
        } else {
            const unsigned short* ap = (const unsigned short*)Av + (size_t)rA * K + quad * 8;
#pragma unroll
            for (int s = 0; s < KS; s++) a[s] = *(const bf8_t*)(ap + s * 32);
        }

        int row = base + quad * 4;
#pragma unroll
        for (int ct = 0; ct < M / 16; ct++) {
            const unsigned short* bp = Bs + (ct * 16 + l15) * ST + quad * 8;
            f4_t acc = {0.f, 0.f, 0.f, 0.f};
#pragma unroll
            for (int s = 0; s < KS; s++) {
                bf8_t b = *(const bf8_t*)(bp + s * 32);
                acc = __builtin_amdgcn_mfma_f32_16x16x32_bf16(a[s], b, acc, 0, 0, 0);
            }
            int colg = ct * 16 + l15;
#pragma unroll
            for (int r = 0; r < 4; r++) {
                if (row + r < n) Yb[(size_t)(row + r) * M + colg] = f2bf(acc[r]);
            }
        }
    }
}

// ---------------- head GEMM v3: out = Z @ [Wmu|Wls] + bias, fp32, split outputs ----------------
__global__ __launch_bounds__(TPB) void k_gemm_out3(const unsigned short* __restrict__ Z,
                                                   const unsigned short* __restrict__ WT,
                                                   const float* __restrict__ bmu,
                                                   const float* __restrict__ bls,
                                                   float* __restrict__ out, int n, int nt) {
    constexpr int K = 64, M = 64, KS = 2, ST = K + 8;
    __shared__ unsigned short Bs[M * ST];
    for (int i = threadIdx.x * 8; i < M * K; i += TPB * 8) {
        int m = i / K, k = i - m * K;
        *(us8_t*)(Bs + m * ST + k) = *(const us8_t*)(WT + i);
    }
    __syncthreads();

    int lane = threadIdx.x & 63;
    int wave = threadIdx.x >> 6;
    int quad = lane >> 4;
    int l15  = lane & 15;

    for (int tile = blockIdx.x; tile < nt; tile += gridDim.x) {
        int base = tile * 64 + wave * 16;
        int rA = base + l15; if (rA > n - 1) rA = n - 1;
        const unsigned short* ap = Z + (size_t)rA * K + quad * 8;
        bf8_t a[KS];
#pragma unroll
        for (int s = 0; s < KS; s++) a[s] = *(const bf8_t*)(ap + s * 32);

        int row = base + quad * 4;
#pragma unroll
        for (int ct = 0; ct < M / 16; ct++) {
            const unsigned short* bp = Bs + (ct * 16 + l15) * ST + quad * 8;
            f4_t acc = {0.f, 0.f, 0.f, 0.f};
#pragma unroll
            for (int s = 0; s < KS; s++) {
                bf8_t b = *(const bf8_t*)(bp + s * 32);
                acc = __builtin_amdgcn_mfma_f32_16x16x32_bf16(a[s], b, acc, 0, 0, 0);
            }
            int colg = ct * 16 + l15;
            float bias = (colg < 32) ? bmu[colg] : bls[colg - 32];
            float* dst = (colg < 32) ? (out + colg) : (out + (size_t)n * 32 + (colg - 32));
#pragma unroll
            for (int r = 0; r < 4; r++) {
                if (row + r < n) dst[(size_t)(row + r) * 32] = acc[r] + bias;
            }
        }
    }
}

// ---------------- ClusterGCN aggregation (bf16 in/out) ----------------
// AB: n x 2*MF bf16 rows [y | r].  Hb[i] = bf16( s * relu( dinv[i]*(sum_{src->i} y[src] + y[i])
//                                                          + r[i] + bias ) ),  s = SCALE?dis[i]:1
template <int MF, int GRP, bool SCALE>
__global__ __launch_bounds__(TPB) void k_aggc(const unsigned short* __restrict__ AB,
                                              const float* __restrict__ bias,
                                              const float* __restrict__ dinv,
                                              const float* __restrict__ dis,
                                              const int* __restrict__ rowptr,
                                              const int* __restrict__ col,
                                              unsigned short* __restrict__ Hb, int n) {
    constexpr int LD = 2 * MF;
    int g = blockIdx.x * (TPB / GRP) + threadIdx.x / GRP;
    int l = threadIdx.x & (GRP - 1);
    if (g >= n) return;
    int c = l * 8;
    if (c >= MF) return;
    int r0 = rowptr[g], r1 = rowptr[g + 1];
    float acc[8];
    {
        bf8_t v = *(const bf8_t*)(AB + (size_t)g * LD + c);
#pragma unroll
        for (int j = 0; j < 8; j++) acc[j] = bf2f((unsigned short)v[j]);
    }
    int e = r0;
    for (; e + 4 <= r1; e += 4) {          // 4-way MLP unroll
        int s0 = col[e], s1 = col[e + 1], s2 = col[e + 2], s3 = col[e + 3];
        bf8_t v0 = *(const bf8_t*)(AB + (size_t)s0 * LD + c);
        bf8_t v1 = *(const bf8_t*)(AB + (size_t)s1 * LD + c);
        bf8_t v2 = *(const bf8_t*)(AB + (size_t)s2 * LD + c);
        bf8_t v3 = *(const bf8_t*)(AB + (size_t)s3 * LD + c);
#pragma unroll
        for (int j = 0; j < 8; j++)
            acc[j] += (bf2f((unsigned short)v0[j]) + bf2f((unsigned short)v1[j]))
                    + (bf2f((unsigned short)v2[j]) + bf2f((unsigned short)v3[j]));
    }
    for (; e < r1; ++e) {
        int s = col[e];
        bf8_t v = *(const bf8_t*)(AB + (size_t)s * LD + c);
#pragma unroll
        for (int j = 0; j < 8; j++) acc[j] += bf2f((unsigned short)v[j]);
    }
    float di = dinv[g];
    float sc = SCALE ? dis[g] : 1.0f;
    bf8_t rr = *(const bf8_t*)(AB + (size_t)g * LD + MF + c);
    us8_t o;
#pragma unroll
    for (int j = 0; j < 8; j++) {
        float h = fmaxf(acc[j] * di + bf2f((unsigned short)rr[j]) + bias[c + j], 0.f);
        o[j] = f2bf(SCALE ? sc * h : h);
    }
    *(us8_t*)(Hb + (size_t)g * MF + c) = o;
}

// ---------------- head aggregation: Z[g] = bf16( dis[g] * (sum_{src->g} H2s[src] + H2s[g]) ) ----
// H2s rows are pre-scaled by dis (written by layer-2 epilogue), so no per-edge dis load.
__global__ __launch_bounds__(TPB) void k_agghead(const unsigned short* __restrict__ H2s,
                                                 const float* __restrict__ dis,
                                                 const int* __restrict__ rowptr,
                                                 const int* __restrict__ col,
                                                 unsigned short* __restrict__ Z, int n) {
    const int GRP = 8;
    int g = blockIdx.x * (TPB / GRP) + threadIdx.x / GRP;
    int l = threadIdx.x & (GRP - 1);
    if (g >= n) return;
    int c = l * 8;
    int r0 = rowptr[g], r1 = rowptr[g + 1];
    float acc[8];
    {
        bf8_t v = *(const bf8_t*)(H2s + (size_t)g * 64 + c);
#pragma unroll
        for (int j = 0; j < 8; j++) acc[j] = bf2f((unsigned short)v[j]);
    }
    int e = r0;
    for (; e + 4 <= r1; e += 4) {
        int s0 = col[e], s1 = col[e + 1], s2 = col[e + 2], s3 = col[e + 3];
        bf8_t v0 = *(const bf8_t*)(H2s + (size_t)s0 * 64 + c);
        bf8_t v1 = *(const bf8_t*)(H2s + (size_t)s1 * 64 + c);
        bf8_t v2 = *(const bf8_t*)(H2s + (size_t)s2 * 64 + c);
        bf8_t v3 = *(const bf8_t*)(H2s + (size_t)s3 * 64 + c);
#pragma unroll
        for (int j = 0; j < 8; j++)
            acc[j] += (bf2f((unsigned short)v0[j]) + bf2f((unsigned short)v1[j]))
                    + (bf2f((unsigned short)v2[j]) + bf2f((unsigned short)v3[j]));
    }
    for (; e < r1; ++e) {
        int s = col[e];
        bf8_t v = *(const bf8_t*)(H2s + (size_t)s * 64 + c);
#pragma unroll
        for (int j = 0; j < 8; j++) acc[j] += bf2f((unsigned short)v[j]);
    }
    float dg = dis[g];
    us8_t o;
#pragma unroll
    for (int j = 0; j < 8; j++) o[j] = f2bf(dg * acc[j]);
    *(us8_t*)(Z + (size_t)g * 64 + c) = o;
}

// ---------------- launch ----------------

extern "C" void kernel_launch(void* const* d_in, const int* in_sizes, int n_in,
                              void* d_out, int out_size, void* d_ws, size_t ws_size,
                              hipStream_t stream) {
    const float* x   = (const float*)d_in[0];
    const int*   ei  = (const int*)d_in[1];
    const float* W1  = (const float*)d_in[2];
    const float* b1  = (const float*)d_in[3];
    const float* Wr1 = (const float*)d_in[4];
    const float* W2  = (const float*)d_in[5];
    const float* b2  = (const float*)d_in[6];
    const float* Wr2 = (const float*)d_in[7];
    const float* Wmu = (const float*)d_in[8];
    const float* bmu = (const float*)d_in[9];
    const float* Wls = (const float*)d_in[10];
    const float* bls = (const float*)d_in[11];
    float* out = (float*)d_out;

    const int IN = 128, L1F = 96, L2F = 64;
    const int N = in_sizes[0] / IN;
    const int E = in_sizes[1] / 2;

    char* ws = (char*)d_ws;
    size_t off = 0;
    auto alloc = [&](size_t b) { size_t r = off; off += (b + 255) & ~(size_t)255; return r; };

    const int nb = (N + TPB - 1) / TPB;
    int*   cnt  = (int*)(ws + alloc((size_t)N * 4));
    int*   bsum = (int*)(ws + alloc((size_t)nb * 4));
    int*   rowp = (int*)(ws + alloc((size_t)(N + 1) * 4));
    int*   curs = (int*)(ws + alloc((size_t)N * 4));
    int*   col  = (int*)(ws + alloc((size_t)E * 4));
    float* dinv = (float*)(ws + alloc((size_t)N * 4));
    float* dis  = (float*)(ws + alloc((size_t)N * 4));
    // weight blocks allocated contiguously -> concatenated [W|Wr] views (all sizes %256==0)
    unsigned short* T1  = (unsigned short*)(ws + alloc((size_t)IN  * L1F * 2));
    unsigned short* Tr1 = (unsigned short*)(ws + alloc((size_t)IN  * L1F * 2));
    unsigned short* T2  = (unsigned short*)(ws + alloc((size_t)L1F * L2F * 2));
    unsigned short* Tr2 = (unsigned short*)(ws + alloc((size_t)L1F * L2F * 2));
    unsigned short* Tmu = (unsigned short*)(ws + alloc((size_t)L2F * 32 * 2));
    unsigned short* Tls = (unsigned short*)(ws + alloc((size_t)L2F * 32 * 2));
    unsigned short* AB1 = (unsigned short*)(ws + alloc((size_t)N * 2 * L1F * 2)); // N x 192 bf16
    unsigned short* AB2 = (unsigned short*)(ws + alloc((size_t)N * 2 * L2F * 2)); // N x 128 bf16
    unsigned short* Hb1 = (unsigned short*)(ws + alloc((size_t)N * L1F * 2));     // relu'd h1
    unsigned short* H2s = (unsigned short*)(ws + alloc((size_t)N * L2F * 2));     // dis-scaled h2
    unsigned short* Zag = (unsigned short*)(ws + alloc((size_t)N * L2F * 2));     // aggregated head input

    hipMemsetAsync(cnt, 0, (size_t)N * 4, stream);

    dim3 eg((E + TPB - 1) / TPB);
    k_count<<<eg, TPB, 0, stream>>>(ei, E, cnt);
    k_blocksum<<<nb, TPB, 0, stream>>>(cnt, N, bsum);
    k_scan_bsum<<<1, 512, 0, stream>>>(bsum, nb);
    k_rowptr<<<nb, TPB, 0, stream>>>(cnt, bsum, N, E, rowp, curs, dinv, dis);
    k_fill<<<eg, TPB, 0, stream>>>(ei, E, curs, col);

    k_wconv<<<dim3(48, 6), TPB, 0, stream>>>(W1, Wr1, W2, Wr2, Wmu, Wls,
                                             T1, Tr1, T2, Tr2, Tmu, Tls);

    const int nt = (N + 63) / 64;
    // layer 1: AB1 = x @ [W1|Wr1] (fused fp32->bf16 on A), Hb1 = relu(dinv*agg(y) + r + b1)
    // 52 KB LDS -> 3 blocks/CU -> grid 768
    k_gemm3<128, 192, true><<<768, TPB, 0, stream>>>(x, T1, AB1, N, nt);
    k_aggc<96, 16, false><<<(N + 15) / 16, TPB, 0, stream>>>(AB1, b1, dinv, dis, rowp, col, Hb1, N);

    // layer 2: AB2 = h1 @ [W2|Wr2], H2s = dis * relu(dinv*agg(y) + r + b2)
    k_gemm3<96, 128, false><<<1024, TPB, 0, stream>>>(Hb1, T2, AB2, N, nt);
    k_aggc<64, 8, true><<<(N + 31) / 32, TPB, 0, stream>>>(AB2, b2, dinv, dis, rowp, col, H2s, N);

    // heads: Zag = dis * (agg H2s + H2s), out = Zag @ [Wmu|Wls] + bias
    k_agghead<<<(N + 31) / 32, TPB, 0, stream>>>(H2s, dis, rowp, col, Zag, N);
    k_gemm_out3<<<1024, TPB, 0, stream>>>(Zag, Tmu, bmu, bls, out, N, nt);
}